// Round 1
// baseline (1834.145 us; speedup 1.0000x reference)
//
#include <hip/hip_runtime.h>
#include <hip/hip_bf16.h>

// Problem constants
#define EMB 512
#define HID 512
#define UNITS 512
#define BS 1024
#define SEQ 360

typedef __attribute__((ext_vector_type(4))) float f32x4;
typedef __attribute__((ext_vector_type(8))) short bf16x8;

__device__ __forceinline__ unsigned short f2bf(float f) {
    unsigned int u = __float_as_uint(f);
    u += 0x7fffu + ((u >> 16) & 1u);   // round-to-nearest-even
    return (unsigned short)(u >> 16);
}

// ---------------- Kernel 0: convert W1 [512x512] fp32 -> bf16 ----------------
__global__ __launch_bounds__(256) void k_convert_w1(const float* __restrict__ w1,
                                                    unsigned short* __restrict__ w1bf) {
    int i = (blockIdx.x * 256 + threadIdx.x) * 4;
    float4 v = *(const float4*)(w1 + i);
    ushort4 o;
    o.x = f2bf(v.x); o.y = f2bf(v.y); o.z = f2bf(v.z); o.w = f2bf(v.w);
    *(ushort4*)(w1bf + i) = o;
}

// ---------------- Kernel 1: h_proj = relu(hidden @ W2^T + b2) ----------------
// grid 256, block 256; each block does 4 batches x 512 units (fp32 VALU, small)
__global__ __launch_bounds__(256) void k_hproj(const float* __restrict__ hidden,
                                               const float* __restrict__ w2,
                                               const float* __restrict__ b2,
                                               float* __restrict__ hp) {
    __shared__ float hid[4 * 512];
    int t = threadIdx.x;
    int b0 = blockIdx.x * 4;
    const float4* src = (const float4*)(hidden + (size_t)b0 * 512);
    ((float4*)hid)[t * 2] = src[t * 2];
    ((float4*)hid)[t * 2 + 1] = src[t * 2 + 1];
    __syncthreads();
    int u0 = t, u1 = t + 256;
    float acc0[4] = {0.f, 0.f, 0.f, 0.f};
    float acc1[4] = {0.f, 0.f, 0.f, 0.f};
    const float4* w2_0 = (const float4*)(w2 + (size_t)u0 * 512);
    const float4* w2_1 = (const float4*)(w2 + (size_t)u1 * 512);
    const float4* h4 = (const float4*)hid;
    for (int k = 0; k < 128; ++k) {
        float4 a = w2_0[k];
        float4 c = w2_1[k];
#pragma unroll
        for (int bb = 0; bb < 4; ++bb) {
            float4 hv = h4[bb * 128 + k];
            acc0[bb] += a.x * hv.x + a.y * hv.y + a.z * hv.z + a.w * hv.w;
            acc1[bb] += c.x * hv.x + c.y * hv.y + c.z * hv.z + c.w * hv.w;
        }
    }
    float bias0 = b2[u0], bias1 = b2[u1];
#pragma unroll
    for (int bb = 0; bb < 4; ++bb) {
        hp[(size_t)(b0 + bb) * 512 + u0] = fmaxf(acc0[bb] + bias0, 0.f);
        hp[(size_t)(b0 + bb) * 512 + u1] = fmaxf(acc1[bb] + bias1, 0.f);
    }
}

// ---------------- Kernel 2: fused scores ----------------
// score[b,s] = sum_u tanh(relu(features[b,s,:]·W1[u,:] + b1[u]) + hp[b,u]) * V[u]
// Grid: 1024 batches * 12 tiles of 32 rows. Block 256 = 4 waves.
// Wave w owns units [w*128, w*128+128): 2 m-blocks x 8 n-blocks of 16x16x32 MFMA.
#define MT 32
#define KT 64
#define LDA 72   // padded LDS stride (bf16 elems): 144B, 16B-aligned, 2-way banks only

__global__ __launch_bounds__(256) void k_score(const float* __restrict__ F,
                                               const unsigned short* __restrict__ W1bf,
                                               const float* __restrict__ b1,
                                               const float* __restrict__ hp,
                                               const float* __restrict__ Vw,
                                               float* __restrict__ scores) {
    __shared__ unsigned short lsA[MT * LDA];
    __shared__ float lds_part[4][MT];

    int t = threadIdx.x;
    int wave = t >> 6, lane = t & 63;
    int col = lane & 15, quad = lane >> 4;
    int tile = blockIdx.x % 12;
    int b = blockIdx.x / 12;
    int s0 = tile * MT;

    f32x4 zero = {0.f, 0.f, 0.f, 0.f};
    f32x4 acc[2][8];
#pragma unroll
    for (int mb = 0; mb < 2; ++mb)
#pragma unroll
        for (int nb = 0; nb < 8; ++nb) acc[mb][nb] = zero;

    // staging: thread -> (row, k-part)
    int srow = t >> 3;           // 0..31
    int kp = (t & 7) * 8;        // 0,8,..,56
    int sIdx = s0 + srow;
    if (sIdx > 359) sIdx = 359;  // clamp (masked at score write)
    const float* Fr = F + ((size_t)(b * 360 + sIdx) * 512 + kp);
    unsigned short* wdst = &lsA[srow * LDA + kp];

    int uBase = wave * 128 + col;

    for (int k0 = 0; k0 < 512; k0 += KT) {
        __syncthreads();
        float4 v0 = *(const float4*)(Fr + k0);
        float4 v1 = *(const float4*)(Fr + k0 + 4);
        union { bf16x8 v; unsigned short s[8]; } pk;
        pk.s[0] = f2bf(v0.x); pk.s[1] = f2bf(v0.y);
        pk.s[2] = f2bf(v0.z); pk.s[3] = f2bf(v0.w);
        pk.s[4] = f2bf(v1.x); pk.s[5] = f2bf(v1.y);
        pk.s[6] = f2bf(v1.z); pk.s[7] = f2bf(v1.w);
        *(bf16x8*)wdst = pk.v;
        __syncthreads();
#pragma unroll
        for (int kk = 0; kk < KT; kk += 32) {
            bf16x8 afrag[2];
#pragma unroll
            for (int mb = 0; mb < 2; ++mb)
                afrag[mb] = *(const bf16x8*)&lsA[(mb * 16 + col) * LDA + kk + quad * 8];
#pragma unroll
            for (int nb = 0; nb < 8; ++nb) {
                bf16x8 bfrag = *(const bf16x8*)&W1bf[(size_t)(uBase + nb * 16) * 512 + k0 + kk + quad * 8];
#pragma unroll
                for (int mb = 0; mb < 2; ++mb)
                    acc[mb][nb] = __builtin_amdgcn_mfma_f32_16x16x32_bf16(afrag[mb], bfrag, acc[mb][nb], 0, 0, 0);
            }
        }
    }

    // epilogue: x = tanh(relu(acc + b1) + hp) * V ; reduce over u
    float hpv[8], b1v[8], vv[8];
#pragma unroll
    for (int nb = 0; nb < 8; ++nb) {
        int u = uBase + nb * 16;
        hpv[nb] = hp[(size_t)b * 512 + u];
        b1v[nb] = b1[u];
        vv[nb] = Vw[u];
    }
#pragma unroll
    for (int mb = 0; mb < 2; ++mb) {
#pragma unroll
        for (int r = 0; r < 4; ++r) {
            float p = 0.f;
#pragma unroll
            for (int nb = 0; nb < 8; ++nb) {
                float x = fmaxf(acc[mb][nb][r] + b1v[nb], 0.f) + hpv[nb];
                // x >= 0 always: tanh(x) = 1 - 2/(exp(2x)+1), robust to overflow
                float e = __expf(2.0f * x);
                float th = 1.0f - 2.0f / (e + 1.0f);
                p += th * vv[nb];
            }
            p += __shfl_xor(p, 1);
            p += __shfl_xor(p, 2);
            p += __shfl_xor(p, 4);
            p += __shfl_xor(p, 8);
            if (col == 0) lds_part[wave][mb * 16 + quad * 4 + r] = p;
        }
    }
    __syncthreads();
    if (t < MT) {
        float s = lds_part[0][t] + lds_part[1][t] + lds_part[2][t] + lds_part[3][t];
        int sg = s0 + t;
        if (sg < 360) scores[(size_t)b * 360 + sg] = s;  // V_b dropped: softmax shift-invariant
    }
}

// ---------------- Kernel 3: softmax over seq + context ----------------
// grid 1024 (one block per batch), block 256
__global__ __launch_bounds__(256) void k_softmax_ctx(const float* __restrict__ F,
                                                     const float* __restrict__ scores,
                                                     float* __restrict__ outc,
                                                     float* __restrict__ outw) {
    __shared__ float wL[SEQ];
    __shared__ float red[8];
    __shared__ f32x4 cross[128];
    int t = threadIdx.x;
    int b = blockIdx.x;
    int lane = t & 63, wid = t >> 6;

    float sa = (t < SEQ) ? scores[(size_t)b * SEQ + t] : -1e30f;
    float sb = (t + 256 < SEQ) ? scores[(size_t)b * SEQ + t + 256] : -1e30f;
    float m = fmaxf(sa, sb);
#pragma unroll
    for (int off = 32; off; off >>= 1) m = fmaxf(m, __shfl_xor(m, off));
    if (lane == 0) red[wid] = m;
    __syncthreads();
    m = fmaxf(fmaxf(red[0], red[1]), fmaxf(red[2], red[3]));

    float e0 = (t < SEQ) ? __expf(sa - m) : 0.f;
    float e1 = (t + 256 < SEQ) ? __expf(sb - m) : 0.f;
    float sum = e0 + e1;
#pragma unroll
    for (int off = 32; off; off >>= 1) sum += __shfl_xor(sum, off);
    if (lane == 0) red[4 + wid] = sum;
    __syncthreads();
    float tot = red[4] + red[5] + red[6] + red[7];
    float inv = 1.0f / tot;

    if (t < SEQ) {
        float w = e0 * inv;
        wL[t] = w;
        outw[(size_t)b * SEQ + t] = w;
    }
    if (t + 256 < SEQ) {
        float w = e1 * inv;
        wL[t + 256] = w;
        outw[(size_t)b * SEQ + t + 256] = w;
    }
    __syncthreads();

    // context[b, :] = sum_s w[s] * F[b, s, :]; 2 s-halves x 128 float4 lanes
    int half = t >> 7, c4 = t & 127;
    const f32x4* Fb = (const f32x4*)(F + (size_t)b * SEQ * 512);
    f32x4 a = {0.f, 0.f, 0.f, 0.f};
    for (int s = half; s < SEQ; s += 2) a += wL[s] * Fb[s * 128 + c4];
    if (half) cross[c4] = a;
    __syncthreads();
    if (!half) {
        f32x4 r = a + cross[c4];
        ((f32x4*)outc)[(size_t)b * 128 + c4] = r;
    }
}

// ---------------- Launch ----------------
extern "C" void kernel_launch(void* const* d_in, const int* in_sizes, int n_in,
                              void* d_out, int out_size, void* d_ws, size_t ws_size,
                              hipStream_t stream) {
    const float* hidden   = (const float*)d_in[0];
    const float* features = (const float*)d_in[1];
    const float* W1_w     = (const float*)d_in[2];
    const float* W1_b     = (const float*)d_in[3];
    const float* W2_w     = (const float*)d_in[4];
    const float* W2_b     = (const float*)d_in[5];
    const float* V_w      = (const float*)d_in[6];
    // V_b (d_in[7]) unused: constant shift cancels in softmax.

    float* outc = (float*)d_out;                    // [1024, 512]
    float* outw = (float*)d_out + (size_t)BS * EMB; // [1024, 360]

    char* ws = (char*)d_ws;
    unsigned short* w1bf = (unsigned short*)ws;                       // 512 KB
    float* hp      = (float*)(ws + 524288);                           // 2 MB
    float* scoresW = (float*)(ws + 524288 + 2097152);                 // 1.41 MB

    hipLaunchKernelGGL(k_convert_w1, dim3(256), dim3(256), 0, stream, W1_w, w1bf);
    hipLaunchKernelGGL(k_hproj, dim3(256), dim3(256), 0, stream, hidden, W2_w, W2_b, hp);
    hipLaunchKernelGGL(k_score, dim3(BS * 12), dim3(256), 0, stream,
                       features, w1bf, W1_b, hp, V_w, scoresW);
    hipLaunchKernelGGL(k_softmax_ctx, dim3(BS), dim3(256), 0, stream,
                       features, scoresW, outc, outw);
}

// Round 2
// 1457.803 us; speedup vs baseline: 1.2582x; 1.2582x over previous
//
#include <hip/hip_runtime.h>
#include <hip/hip_bf16.h>

#define EMB 512
#define HID 512
#define UNITS 512
#define BS 1024
#define SEQ 360

typedef __attribute__((ext_vector_type(4))) float f32x4;
typedef __attribute__((ext_vector_type(8))) short bf16x8;

__device__ __forceinline__ unsigned int pk2bf(float lo, float hi) {
    unsigned int ulo = __float_as_uint(lo);
    unsigned int uhi = __float_as_uint(hi);
    ulo += 0x7fffu + ((ulo >> 16) & 1u);   // rne
    uhi += 0x7fffu + ((uhi >> 16) & 1u);
    return (ulo >> 16) | (uhi & 0xffff0000u);
}

// ---------------- Kernel 0: W1 fp32 -> bf16 ----------------
__global__ __launch_bounds__(256) void k_convert_w1(const float* __restrict__ w1,
                                                    unsigned short* __restrict__ w1bf) {
    int i = (blockIdx.x * 256 + threadIdx.x) * 4;
    float4 v = *(const float4*)(w1 + i);
    uint2 o;
    o.x = pk2bf(v.x, v.y);
    o.y = pk2bf(v.z, v.w);
    *(uint2*)(w1bf + i) = o;
}

// ---------------- Kernel 1: h_proj = relu(hidden @ W2^T + b2) ----------------
__global__ __launch_bounds__(256) void k_hproj(const float* __restrict__ hidden,
                                               const float* __restrict__ w2,
                                               const float* __restrict__ b2,
                                               float* __restrict__ hp) {
    __shared__ float hid[4 * 512];
    int t = threadIdx.x;
    int b0 = blockIdx.x * 4;
    const float4* src = (const float4*)(hidden + (size_t)b0 * 512);
    ((float4*)hid)[t * 2] = src[t * 2];
    ((float4*)hid)[t * 2 + 1] = src[t * 2 + 1];
    __syncthreads();
    int u0 = t, u1 = t + 256;
    float acc0[4] = {0.f, 0.f, 0.f, 0.f};
    float acc1[4] = {0.f, 0.f, 0.f, 0.f};
    const float4* w2_0 = (const float4*)(w2 + (size_t)u0 * 512);
    const float4* w2_1 = (const float4*)(w2 + (size_t)u1 * 512);
    const float4* h4 = (const float4*)hid;
    for (int k = 0; k < 128; ++k) {
        float4 a = w2_0[k];
        float4 c = w2_1[k];
#pragma unroll
        for (int bb = 0; bb < 4; ++bb) {
            float4 hv = h4[bb * 128 + k];
            acc0[bb] += a.x * hv.x + a.y * hv.y + a.z * hv.z + a.w * hv.w;
            acc1[bb] += c.x * hv.x + c.y * hv.y + c.z * hv.z + c.w * hv.w;
        }
    }
    float bias0 = b2[u0], bias1 = b2[u1];
#pragma unroll
    for (int bb = 0; bb < 4; ++bb) {
        hp[(size_t)(b0 + bb) * 512 + u0] = fmaxf(acc0[bb] + bias0, 0.f);
        hp[(size_t)(b0 + bb) * 512 + u1] = fmaxf(acc1[bb] + bias1, 0.f);
    }
}

// ---------------- Kernel 2: fused scores ----------------
// M=64 rows per block, N=512 (4 waves x 128u), KT=64, A reg-prefetch across barrier.
#define MT 64
#define KT 64

__global__ __launch_bounds__(256, 2) void k_score(const float* __restrict__ F,
                                                  const unsigned short* __restrict__ W1bf,
                                                  const float* __restrict__ b1,
                                                  const float* __restrict__ hp,
                                                  const float* __restrict__ Vw,
                                                  float* __restrict__ scores) {
    // A tile: 64 rows x 64 bf16, stored as 8 chunks of 16B per row, XOR-swizzled
    __shared__ uint4 lsA[MT * 8];          // 8 KB
    __shared__ float lds_part[4][MT];

    int t = threadIdx.x;
    int wave = t >> 6, lane = t & 63;
    int col = lane & 15, quad = lane >> 4;
    int tile = blockIdx.x % 6;
    int b = blockIdx.x / 6;
    int s0 = tile * MT;

    f32x4 acc[4][8];
#pragma unroll
    for (int mb = 0; mb < 4; ++mb)
#pragma unroll
        for (int nb = 0; nb < 8; ++nb) {
            f32x4 z = {0.f, 0.f, 0.f, 0.f};
            acc[mb][nb] = z;
        }

    // staging map: 4 threads per row, each loads 16 consecutive floats
    int srow = t >> 2;              // 0..63
    int kpi = t & 3;                // 16-float column group
    int sIdx = s0 + srow;
    if (sIdx > 359) sIdx = 359;     // clamp; writes masked
    const float* Fr = F + ((size_t)(b * 360 + sIdx) * 512 + kpi * 16);
    int sw = srow & 7;
    int c0 = (2 * kpi) ^ sw;        // swizzled chunk indices
    int c1 = (2 * kpi + 1) ^ sw;
    uint4* wdst0 = &lsA[srow * 8 + c0];
    uint4* wdst1 = &lsA[srow * 8 + c1];

    int uBase = wave * 128 + col;
    int cw = col & 7;

    // prologue prefetch (k0 = 0)
    float4 a0 = *(const float4*)(Fr);
    float4 a1 = *(const float4*)(Fr + 4);
    float4 a2 = *(const float4*)(Fr + 8);
    float4 a3 = *(const float4*)(Fr + 12);

#pragma unroll
    for (int k0 = 0; k0 < 512; k0 += KT) {
        // pack current tile (registers only, before barrier)
        uint4 u0, u1;
        u0.x = pk2bf(a0.x, a0.y); u0.y = pk2bf(a0.z, a0.w);
        u0.z = pk2bf(a1.x, a1.y); u0.w = pk2bf(a1.z, a1.w);
        u1.x = pk2bf(a2.x, a2.y); u1.y = pk2bf(a2.z, a2.w);
        u1.z = pk2bf(a3.x, a3.y); u1.w = pk2bf(a3.z, a3.w);
        __syncthreads();            // all reads of previous tile done
        *wdst0 = u0;
        *wdst1 = u1;
        // prefetch next A tile into registers (overlaps MFMA below)
        float4 n0 = {0.f,0.f,0.f,0.f}, n1 = n0, n2 = n0, n3 = n0;
        if (k0 + KT < 512) {
            const float* Fn = Fr + k0 + KT;
            n0 = *(const float4*)(Fn);
            n1 = *(const float4*)(Fn + 4);
            n2 = *(const float4*)(Fn + 8);
            n3 = *(const float4*)(Fn + 12);
        }
        __syncthreads();            // staging visible
#pragma unroll
        for (int kk = 0; kk < KT; kk += 32) {
            int kkc = kk >> 3;      // chunk base within tile (0 or 4)
            bf16x8 bfrag[8];
#pragma unroll
            for (int nb = 0; nb < 8; ++nb)
                bfrag[nb] = *(const bf16x8*)&W1bf[(size_t)(uBase + nb * 16) * 512 + k0 + kk + quad * 8];
            bf16x8 afrag[4];
#pragma unroll
            for (int mb = 0; mb < 4; ++mb)
                afrag[mb] = *(const bf16x8*)&lsA[(mb * 16 + col) * 8 + ((kkc + quad) ^ cw)];
#pragma unroll
            for (int nb = 0; nb < 8; ++nb)
#pragma unroll
                for (int mb = 0; mb < 4; ++mb)
                    acc[mb][nb] = __builtin_amdgcn_mfma_f32_16x16x32_bf16(afrag[mb], bfrag[nb], acc[mb][nb], 0, 0, 0);
        }
        a0 = n0; a1 = n1; a2 = n2; a3 = n3;
    }

    // epilogue: sum_u tanh(relu(acc+b1)+hp) * V  ;  tanh(x) = 1 - 2/(exp(2x)+1)
    float b1v[8], hpv[8], vv[8];
    float sumv = 0.f;
#pragma unroll
    for (int nb = 0; nb < 8; ++nb) {
        int u = uBase + nb * 16;
        b1v[nb] = b1[u];
        hpv[nb] = hp[(size_t)b * 512 + u];
        vv[nb] = Vw[u];
        sumv += vv[nb];
    }
#pragma unroll
    for (int mb = 0; mb < 4; ++mb) {
#pragma unroll
        for (int r = 0; r < 4; ++r) {
            float p2 = 0.f;
#pragma unroll
            for (int nb = 0; nb < 8; ++nb) {
                float x = fmaxf(acc[mb][nb][r] + b1v[nb], 0.f) + hpv[nb];
                float e = __builtin_amdgcn_exp2f(x * 2.885390082f);   // exp(2x)
                float rc = __builtin_amdgcn_rcpf(e + 1.0f);
                p2 += vv[nb] * rc;
            }
            float p = sumv - 2.0f * p2;   // sum_nb v*(1-2/(e+1))
            p += __shfl_xor(p, 1);
            p += __shfl_xor(p, 2);
            p += __shfl_xor(p, 4);
            p += __shfl_xor(p, 8);
            if (col == 0) lds_part[wave][mb * 16 + quad * 4 + r] = p;
        }
    }
    __syncthreads();
    if (t < MT) {
        float s = lds_part[0][t] + lds_part[1][t] + lds_part[2][t] + lds_part[3][t];
        int sg = s0 + t;
        if (sg < 360) scores[(size_t)b * 360 + sg] = s;
    }
}

// ---------------- Kernel 3: softmax + context (4 emb-chunks per batch) ----------------
__global__ __launch_bounds__(256) void k_softctx(const float* __restrict__ F,
                                                 const float* __restrict__ scores,
                                                 float* __restrict__ outc,
                                                 float* __restrict__ outw) {
    __shared__ float wL[SEQ];
    __shared__ float red[8];
    __shared__ f32x4 red8[8][32];
    int t = threadIdx.x;
    int b = blockIdx.x >> 2;
    int chunk = blockIdx.x & 3;
    int lane = t & 63, wid = t >> 6;

    float sa = (t < SEQ) ? scores[(size_t)b * SEQ + t] : -1e30f;
    float sb = (t + 256 < SEQ) ? scores[(size_t)b * SEQ + t + 256] : -1e30f;
    float m = fmaxf(sa, sb);
#pragma unroll
    for (int off = 32; off; off >>= 1) m = fmaxf(m, __shfl_xor(m, off));
    if (lane == 0) red[wid] = m;
    __syncthreads();
    m = fmaxf(fmaxf(red[0], red[1]), fmaxf(red[2], red[3]));

    const float L2E = 1.4426950408889634f;
    float e0 = (t < SEQ) ? __builtin_amdgcn_exp2f((sa - m) * L2E) : 0.f;
    float e1 = (t + 256 < SEQ) ? __builtin_amdgcn_exp2f((sb - m) * L2E) : 0.f;
    float sum = e0 + e1;
#pragma unroll
    for (int off = 32; off; off >>= 1) sum += __shfl_xor(sum, off);
    if (lane == 0) red[4 + wid] = sum;
    __syncthreads();
    float inv = 1.0f / (red[4] + red[5] + red[6] + red[7]);

    if (t < SEQ) {
        float w = e0 * inv;
        wL[t] = w;
        if (chunk == 0) outw[(size_t)b * SEQ + t] = w;
    }
    if (t + 256 < SEQ) {
        float w = e1 * inv;
        wL[t + 256] = w;
        if (chunk == 0) outw[(size_t)b * SEQ + t + 256] = w;
    }
    __syncthreads();

    // context chunk: 128 floats = 32 f32x4 lanes x 8 s-strips
    int c4 = t & 31, strip = t >> 5;
    const f32x4* Fb = (const f32x4*)F + (size_t)b * SEQ * 128 + chunk * 32 + c4;
    f32x4 a = {0.f, 0.f, 0.f, 0.f};
    for (int s = strip; s < SEQ; s += 8) a += wL[s] * Fb[(size_t)s * 128];
    red8[strip][c4] = a;
    __syncthreads();
    if (t < 32) {
        f32x4 s = red8[0][t];
#pragma unroll
        for (int k = 1; k < 8; ++k) s += red8[k][t];
        ((f32x4*)outc)[(size_t)b * 128 + chunk * 32 + t] = s;
    }
}

// ---------------- Launch ----------------
extern "C" void kernel_launch(void* const* d_in, const int* in_sizes, int n_in,
                              void* d_out, int out_size, void* d_ws, size_t ws_size,
                              hipStream_t stream) {
    const float* hidden   = (const float*)d_in[0];
    const float* features = (const float*)d_in[1];
    const float* W1_w     = (const float*)d_in[2];
    const float* W1_b     = (const float*)d_in[3];
    const float* W2_w     = (const float*)d_in[4];
    const float* W2_b     = (const float*)d_in[5];
    const float* V_w      = (const float*)d_in[6];
    // V_b unused: constant shift cancels in softmax.

    float* outc = (float*)d_out;                    // [1024, 512]
    float* outw = (float*)d_out + (size_t)BS * EMB; // [1024, 360]

    char* ws = (char*)d_ws;
    unsigned short* w1bf = (unsigned short*)ws;                 // 512 KB
    float* hp      = (float*)(ws + 524288);                     // 2 MB
    float* scoresW = (float*)(ws + 524288 + 2097152);           // 1.44 MB

    hipLaunchKernelGGL(k_convert_w1, dim3(256), dim3(256), 0, stream, W1_w, w1bf);
    hipLaunchKernelGGL(k_hproj, dim3(256), dim3(256), 0, stream, hidden, W2_w, W2_b, hp);
    hipLaunchKernelGGL(k_score, dim3(BS * 6), dim3(256), 0, stream,
                       features, w1bf, W1_b, hp, V_w, scoresW);
    hipLaunchKernelGGL(k_softctx, dim3(BS * 4), dim3(256), 0, stream,
                       features, scoresW, outc, outw);
}